// Round 3
// baseline (457.790 us; speedup 1.0000x reference)
//
#include <hip/hip_runtime.h>
#include <math.h>

#define NB 32
#define CB 256
#define HB 56
#define WB 56
#define PLANE 3136           // floats per (n,c) plane
#define PLANE4 784           // float4 per plane
#define CL 56
#define POOLSZ (NB*CB*CL)
#define NCHUNK 1024          // 8-plane chunks
#define TBLN 1792            // table floats per chunk: H0|W0|H1|W1 (448 each)

__device__ inline float wave_sum(float v) {
    #pragma unroll
    for (int o = 32; o; o >>= 1) v += __shfl_xor(v, o, 64);
    return v;
}

// ---------------- Kernel 1: pooling. 4096 blocks x 256 thr, 2 planes, 1 sync ----
__global__ __launch_bounds__(256) void k_pool(const float* __restrict__ x,
        float* __restrict__ ph, float* __restrict__ pw,
        float* __restrict__ mh, float* __restrict__ mw, float* __restrict__ gap) {
    __shared__ float tile[2 * 3192];          // two 56x57 planes, 25.5 KB
    const int t = threadIdx.x, wv = t >> 6, ln = t & 63;
    const int pA = blockIdx.x * 2;
    const float4* x4 = (const float4*)(x + (size_t)pA * PLANE);
    for (int j = t; j < 2 * PLANE4; j += 256) {
        float4 v = x4[j];
        int pl = j >= PLANE4, jj = j - pl * PLANE4;
        int h = jj / 14, wq = jj - h * 14;
        float* d = &tile[pl * 3192 + h * 57 + wq * 4];
        d[0] = v.x; d[1] = v.y; d[2] = v.z; d[3] = v.w;
    }
    __syncthreads();
    const int pl = wv >> 1;                   // waves 0,1 -> plane A; 2,3 -> B
    const float* tb = &tile[pl * 3192];
    const size_t pidx = (size_t)(pA + pl) * CL;
    if (!(wv & 1)) {                          // even wave: column scans
        if (ln < CL) {
            float s = 0.f, m = -INFINITY;
            #pragma unroll 8
            for (int h = 0; h < HB; ++h) { float v = tb[h * 57 + ln]; s += v; m = fmaxf(m, v); }
            pw[pidx + ln] = s * (1.f / HB);
            mw[pidx + ln] = m;
        }
    } else {                                  // odd wave: row scans + gap
        float s = 0.f, m = -INFINITY;
        if (ln < CL) {
            #pragma unroll 8
            for (int wq = 0; wq < WB; ++wq) { float v = tb[ln * 57 + wq]; s += v; m = fmaxf(m, v); }
            ph[pidx + ln] = s * (1.f / WB);
            mh[pidx + ln] = m;
        }
        float tot = wave_sum(s);              // lanes >=56 contribute 0
        if (ln == 0) gap[pA + pl] = tot * (1.f / PLANE);
    }
}

// ---------------- Kernel 2: y + gate g + coefficient tables. grid (32,2) --------
__global__ __launch_bounds__(256) void k_branch(
        const float* __restrict__ ph, const float* __restrict__ pw,
        const float* __restrict__ mh, const float* __restrict__ mw,
        const float* __restrict__ gap,
        const float* __restrict__ w1, const float* __restrict__ b1,
        const float* __restrict__ gamma, const float* __restrict__ beta,
        const float* __restrict__ rmean, const float* __restrict__ rvar,
        const float* __restrict__ gw1, const float* __restrict__ gw2,
        const float* __restrict__ gb2,
        const float* __restrict__ wh, const float* __restrict__ bh,
        const float* __restrict__ ww, const float* __restrict__ bw,
        float* __restrict__ tbl, float* __restrict__ g,
        int* __restrict__ counter, int* __restrict__ flag) {
    int n = blockIdx.x;
    int br = blockIdx.y;
    const float* pool_h = br ? mh : ph;
    const float* pool_w = br ? mw : pw;
    __shared__ float tile[CB * 113];          // 113 odd -> conflict-free
    __shared__ float lw1[8 * CB];
    __shared__ float yl[896];                 // y[m][l] for this (n,br)
    __shared__ float hid[64];
    int t = threadIdx.x;

    if (br == 0 && t == 0) { counter[n] = 0; flag[n] = 0; }   // reset sync state

    for (int i = t; i < 8 * CB; i += 256) lw1[i] = w1[i];
    const float4* ph4 = (const float4*)(pool_h + (size_t)n * (CB * CL));
    const float4* pw4 = (const float4*)(pool_w + (size_t)n * (CB * CL));
    for (int j = t; j < 3584; j += 256) {
        int c = j / 14, w4 = (j - c * 14) * 4;
        float4 v = ph4[j];
        float* d = &tile[c * 113 + w4];
        d[0] = v.x; d[1] = v.y; d[2] = v.z; d[3] = v.w;
        v = pw4[j];
        d = &tile[c * 113 + 56 + w4];
        d[0] = v.x; d[1] = v.y; d[2] = v.z; d[3] = v.w;
    }
    __syncthreads();

    int grp = t / 112, l = t - grp * 112;     // grp 0,1 active (4 m each)
    if (grp < 2) {
        int m0 = grp * 4;
        float a0 = 0.f, a1 = 0.f, a2 = 0.f, a3 = 0.f;
        #pragma unroll 8
        for (int c = 0; c < CB; ++c) {
            float v = tile[c * 113 + l];
            a0 += v * lw1[(m0 + 0) * CB + c];
            a1 += v * lw1[(m0 + 1) * CB + c];
            a2 += v * lw1[(m0 + 2) * CB + c];
            a3 += v * lw1[(m0 + 3) * CB + c];
        }
        float acc[4] = {a0, a1, a2, a3};
        #pragma unroll
        for (int k = 0; k < 4; ++k) {
            int m = m0 + k;
            float scale = gamma[m] * rsqrtf(rvar[m] + 1e-5f);
            float val = (acc[k] + b1[m] - rmean[m]) * scale + beta[m];
            yl[m * 112 + l] = fmaxf(val, 0.f);
        }
    }
    if (br == 0 && t >= 128 && t < 192) {     // gate hidden layer (overlaps y)
        int j = t - 128;
        float acc = 0.f;
        for (int c = 0; c < CB; ++c) acc += gap[n * CB + c] * gw1[j * CB + c];
        hid[j] = fmaxf(acc, 0.f);
    }
    __syncthreads();

    if (br == 0 && t == 0) {                  // gate softmax (others do tables)
        float l0 = gb2[0], l1 = gb2[1];
        for (int j = 0; j < 64; ++j) { l0 += hid[j] * gw2[j]; l1 += hid[j] * gw2[64 + j]; }
        float mx = fmaxf(l0, l1);
        float e0 = __expf(l0 - mx), e1 = __expf(l1 - mx);
        float inv = 1.f / (e0 + e1);
        g[n * 2]     = e0 * inv;
        g[n * 2 + 1] = e1 * inv;
    }

    // coefficient tables for all 256 channels of this (n,br): unscaled sigmoids
    for (int idx = t; idx < 14336; idx += 256) {
        int c = idx / 56, l2 = idx - c * 56;
        float hv = bh[c], wvv = bw[c];
        #pragma unroll
        for (int m = 0; m < 8; ++m) {
            hv  += yl[m * 112 + l2]      * wh[c * 8 + m];
            wvv += yl[m * 112 + 56 + l2] * ww[c * 8 + m];
        }
        size_t base = (size_t)(n * 32 + (c >> 3)) * TBLN + (size_t)br * 896 + (c & 7) * 56 + l2;
        tbl[base]       = 1.f / (1.f + __expf(-hv));
        tbl[base + 448] = 1.f / (1.f + __expf(-wvv));
    }
}

// ---------------- Kernel 3: tvec -> s -> out, per-n flag handoff ----------------
__global__ __launch_bounds__(256, 4) void k_mega(const float* __restrict__ x,
        const float* __restrict__ tbl, const float* __restrict__ gbuf,
        const float* __restrict__ cw1, const float* __restrict__ cw2,
        const float* __restrict__ cb2,
        float* __restrict__ tvec, float* __restrict__ sbuf,
        int* __restrict__ counter, int* __restrict__ flag,
        float* __restrict__ out) {
    __shared__ __align__(16) float tb[1792];  // H0|W0(g0-scaled)|H1|W1(g1-scaled)
    __shared__ __align__(16) float ph_[256];
    __shared__ float tvl[256];
    __shared__ float part[32];
    __shared__ float hid[64];
    __shared__ float sS[8];
    __shared__ int lastf;
    const int t = threadIdx.x, wv = t >> 6, ln = t & 63;
    const int gq = blockIdx.x;
    const int q0 = gq * 8, qn = q0 >> 8, qc0 = q0 & 255;

    // load tables, fold g into the W tables
    {
        const float g0 = gbuf[qn * 2], g1 = gbuf[qn * 2 + 1];
        const float4* ts = (const float4*)(tbl + (size_t)gq * TBLN);
        float4* td = (float4*)tb;
        for (int i = t; i < 448; i += 256) {
            float4 v = ts[i];
            float s = (i >= 112 && i < 224) ? g0 : ((i >= 336) ? g1 : 1.f);
            v.x *= s; v.y *= s; v.z *= s; v.w *= s;
            td[i] = v;
        }
    }
    __syncthreads();
    const float* cH0 = tb;
    const float* cW0 = tb + 448;
    const float* cH1 = tb + 896;
    const float* cW1 = tb + 1344;

    // pass 1: tvec[c] = mean(x * attn) for this chunk's 8 channels
    #pragma unroll 1
    for (int i = 0; i < 8; ++i) {
        const float4* xp4 = (const float4*)(x + (size_t)(q0 + i) * PLANE);
        const float4* a4 = (const float4*)(cW0 + i * 56);
        const float4* b4 = (const float4*)(cW1 + i * 56);
        const float* h0p = cH0 + i * 56;
        const float* h1p = cH1 + i * 56;
        float acc = 0.f;
        for (int j = t; j < PLANE4; j += 256) {
            float4 v = xp4[j];
            int h = j / 14, wq = j - h * 14;
            float h0 = h0p[h], h1 = h1p[h];
            float4 a = a4[wq], b = b4[wq];
            acc += v.x * (h0 * a.x + h1 * b.x) + v.y * (h0 * a.y + h1 * b.y)
                 + v.z * (h0 * a.z + h1 * b.z) + v.w * (h0 * a.w + h1 * b.w);
        }
        float s = wave_sum(acc);
        if (ln == 0) part[i * 4 + wv] = s;
    }
    __syncthreads();
    if (t < 8) {
        float v = (part[t * 4] + part[t * 4 + 1] + part[t * 4 + 2] + part[t * 4 + 3]) * (1.f / PLANE);
        __hip_atomic_store(&tvec[q0 + t], v, __ATOMIC_RELEASE, __HIP_MEMORY_SCOPE_AGENT);
    }
    __syncthreads();
    if (t == 0) {
        int prev = __hip_atomic_fetch_add(&counter[qn], 1, __ATOMIC_ACQ_REL, __HIP_MEMORY_SCOPE_AGENT);
        lastf = (prev == 31);
    }
    __syncthreads();

    if (lastf) {                              // last arrival: compute s[256] for qn
        tvl[t] = __hip_atomic_load(&tvec[qn * CB + t], __ATOMIC_ACQUIRE, __HIP_MEMORY_SCOPE_AGENT);
        __syncthreads();
        {
            int j = t & 63, ch = t >> 6;
            const float* wp = cw1 + (size_t)j * CB + ch * 64;
            const float* tv = tvl + ch * 64;
            float a = 0.f;
            #pragma unroll 8
            for (int c = 0; c < 64; ++c) a += tv[c] * wp[c];
            ph_[j * 4 + ch] = a;
        }
        __syncthreads();
        if (t < 64) {
            float4 p = *(const float4*)(ph_ + t * 4);
            hid[t] = fmaxf(p.x + p.y + p.z + p.w, 0.f);
        }
        __syncthreads();
        {
            float a = cb2[t];
            #pragma unroll 8
            for (int j = 0; j < 64; ++j) a += hid[j] * cw2[t * 64 + j];
            float sv = 1.f / (1.f + __expf(-a));
            __hip_atomic_store(&sbuf[qn * CB + t], sv, __ATOMIC_RELEASE, __HIP_MEMORY_SCOPE_AGENT);
        }
        __syncthreads();
        if (t == 0) __hip_atomic_store(&flag[qn], 1, __ATOMIC_RELEASE, __HIP_MEMORY_SCOPE_AGENT);
    }

    if (t == 0) {                             // wait for this n's s to be ready
        while (__hip_atomic_load(&flag[qn], __ATOMIC_ACQUIRE, __HIP_MEMORY_SCOPE_AGENT) == 0)
            __builtin_amdgcn_s_sleep(8);
    }
    __syncthreads();
    if (t < 8)
        sS[t] = __hip_atomic_load(&sbuf[qn * CB + qc0 + t], __ATOMIC_ACQUIRE, __HIP_MEMORY_SCOPE_AGENT);
    __syncthreads();

    // pass 2: out = x * (attn * s + 1)
    #pragma unroll 1
    for (int i = 0; i < 8; ++i) {
        const float sv = sS[i];
        const float4* xp4 = (const float4*)(x + (size_t)(q0 + i) * PLANE);
        float4* op4 = (float4*)(out + (size_t)(q0 + i) * PLANE);
        const float4* a4 = (const float4*)(cW0 + i * 56);
        const float4* b4 = (const float4*)(cW1 + i * 56);
        const float* h0p = cH0 + i * 56;
        const float* h1p = cH1 + i * 56;
        for (int j = t; j < PLANE4; j += 256) {
            float4 v = xp4[j];
            int h = j / 14, wq = j - h * 14;
            float h0 = h0p[h] * sv, h1 = h1p[h] * sv;
            float4 a = a4[wq], b = b4[wq];
            float4 rr;
            rr.x = v.x * (h0 * a.x + h1 * b.x + 1.f);
            rr.y = v.y * (h0 * a.y + h1 * b.y + 1.f);
            rr.z = v.z * (h0 * a.z + h1 * b.z + 1.f);
            rr.w = v.w * (h0 * a.w + h1 * b.w + 1.f);
            op4[j] = rr;
        }
    }
}

extern "C" void kernel_launch(void* const* d_in, const int* in_sizes, int n_in,
                              void* d_out, int out_size, void* d_ws, size_t ws_size,
                              hipStream_t stream) {
    const float* x     = (const float*)d_in[0];
    const float* w1    = (const float*)d_in[1];
    const float* b1    = (const float*)d_in[2];
    const float* gamma = (const float*)d_in[3];
    const float* beta  = (const float*)d_in[4];
    const float* rmean = (const float*)d_in[5];
    const float* rvar  = (const float*)d_in[6];
    const float* wh    = (const float*)d_in[7];
    const float* bh    = (const float*)d_in[8];
    const float* ww    = (const float*)d_in[9];
    const float* bw    = (const float*)d_in[10];
    const float* gw1   = (const float*)d_in[11];
    const float* gw2   = (const float*)d_in[12];
    const float* gb2   = (const float*)d_in[13];
    const float* cw1   = (const float*)d_in[14];
    const float* cw2   = (const float*)d_in[15];
    const float* cb2   = (const float*)d_in[16];
    float* out = (float*)d_out;

    float* w = (float*)d_ws;
    float* ph   = w;                          // POOLSZ each
    float* pw   = ph + POOLSZ;
    float* mh   = pw + POOLSZ;
    float* mw   = mh + POOLSZ;
    float* gap  = mw + POOLSZ;                // NB*CB
    float* tvec = gap + NB * CB;              // NB*CB
    float* sbuf = tvec + NB * CB;             // NB*CB
    float* gbuf = sbuf + NB * CB;             // 64
    float* tbl  = gbuf + 64;                  // NCHUNK * TBLN
    int*   counter = (int*)(tbl + (size_t)NCHUNK * TBLN);   // 32
    int*   flag    = counter + 32;                          // 32

    k_pool<<<4096, 256, 0, stream>>>(x, ph, pw, mh, mw, gap);
    k_branch<<<dim3(NB, 2), 256, 0, stream>>>(ph, pw, mh, mw, gap,
                                              w1, b1, gamma, beta, rmean, rvar,
                                              gw1, gw2, gb2, wh, bh, ww, bw,
                                              tbl, gbuf, counter, flag);
    k_mega<<<NCHUNK, 256, 0, stream>>>(x, tbl, gbuf, cw1, cw2, cb2,
                                       tvec, sbuf, counter, flag, out);
}

// Round 4
// 289.819 us; speedup vs baseline: 1.5796x; 1.5796x over previous
//
#include <hip/hip_runtime.h>
#include <math.h>

#define NB 32
#define CB 256
#define HB 56
#define WB 56
#define PLANE 3136           // floats per (n,c) plane
#define PLANE4 784           // float4 per plane
#define CL 56
#define POOLSZ (NB*CB*CL)
#define NCHUNK 1024          // 8-plane chunks
#define TBLN 1792            // table floats per chunk: H0|W0|H1|W1 (448 each)

__device__ inline float wave_sum(float v) {
    #pragma unroll
    for (int o = 32; o; o >>= 1) v += __shfl_xor(v, o, 64);
    return v;
}

// ---------------- Kernel 1: pooling. 4096 blocks, 2 planes, deep-ILP loads ------
__global__ __launch_bounds__(256) void k_pool(const float* __restrict__ x,
        float* __restrict__ ph, float* __restrict__ pw,
        float* __restrict__ mh, float* __restrict__ mw, float* __restrict__ gap) {
    __shared__ float tile[2 * 3192];          // two 56x57 planes, 25.5 KB
    const int t = threadIdx.x, wv = t >> 6, ln = t & 63;
    const int pA = blockIdx.x * 2;
    const float4* x4 = (const float4*)(x + (size_t)pA * PLANE);

    // issue all 6 (+1 tail) loads before any LDS scatter: 6-deep MLP per thread
    float4 v[6];
    #pragma unroll
    for (int u = 0; u < 6; ++u) v[u] = x4[t + u * 256];
    float4 vt;
    const bool tail = t < 32;
    if (tail) vt = x4[t + 1536];
    #pragma unroll
    for (int u = 0; u < 6; ++u) {
        int j = t + u * 256;
        int pl = j >= PLANE4, jj = j - pl * PLANE4;
        int h = jj / 14, wq = jj - h * 14;
        float* d = &tile[pl * 3192 + h * 57 + wq * 4];
        d[0] = v[u].x; d[1] = v[u].y; d[2] = v[u].z; d[3] = v[u].w;
    }
    if (tail) {
        int j = t + 1536;
        int jj = j - PLANE4;                  // always plane 1
        int h = jj / 14, wq = jj - h * 14;
        float* d = &tile[3192 + h * 57 + wq * 4];
        d[0] = vt.x; d[1] = vt.y; d[2] = vt.z; d[3] = vt.w;
    }
    __syncthreads();

    const int pl = wv >> 1;                   // waves 0,1 -> plane A; 2,3 -> B
    const float* tb = &tile[pl * 3192];
    const size_t pidx = (size_t)(pA + pl) * CL;
    if (!(wv & 1)) {                          // even wave: column scans
        if (ln < CL) {
            float s = 0.f, m = -INFINITY;
            #pragma unroll 8
            for (int h = 0; h < HB; ++h) { float vv = tb[h * 57 + ln]; s += vv; m = fmaxf(m, vv); }
            pw[pidx + ln] = s * (1.f / HB);
            mw[pidx + ln] = m;
        }
    } else {                                  // odd wave: row scans + gap
        float s = 0.f, m = -INFINITY;
        if (ln < CL) {
            #pragma unroll 8
            for (int wq = 0; wq < WB; ++wq) { float vv = tb[ln * 57 + wq]; s += vv; m = fmaxf(m, vv); }
            ph[pidx + ln] = s * (1.f / WB);
            mh[pidx + ln] = m;
        }
        float tot = wave_sum(s);              // lanes >=56 contribute 0
        if (ln == 0) gap[pA + pl] = tot * (1.f / PLANE);
    }
}

// ---------------- Kernel 2: y + gate g + sigmoid tables. grid (32,2) ------------
// (round-3 verified version, counter/flag removed)
__global__ __launch_bounds__(256) void k_branch(
        const float* __restrict__ ph, const float* __restrict__ pw,
        const float* __restrict__ mh, const float* __restrict__ mw,
        const float* __restrict__ gap,
        const float* __restrict__ w1, const float* __restrict__ b1,
        const float* __restrict__ gamma, const float* __restrict__ beta,
        const float* __restrict__ rmean, const float* __restrict__ rvar,
        const float* __restrict__ gw1, const float* __restrict__ gw2,
        const float* __restrict__ gb2,
        const float* __restrict__ wh, const float* __restrict__ bh,
        const float* __restrict__ ww, const float* __restrict__ bw,
        float* __restrict__ tbl, float* __restrict__ g) {
    int n = blockIdx.x;
    int br = blockIdx.y;
    const float* pool_h = br ? mh : ph;
    const float* pool_w = br ? mw : pw;
    __shared__ float tile[CB * 113];          // 113 odd -> conflict-free
    __shared__ float lw1[8 * CB];
    __shared__ float yl[896];                 // y[m][l] for this (n,br)
    __shared__ float hid[64];
    int t = threadIdx.x;

    for (int i = t; i < 8 * CB; i += 256) lw1[i] = w1[i];
    const float4* ph4 = (const float4*)(pool_h + (size_t)n * (CB * CL));
    const float4* pw4 = (const float4*)(pool_w + (size_t)n * (CB * CL));
    for (int j = t; j < 3584; j += 256) {
        int c = j / 14, w4 = (j - c * 14) * 4;
        float4 v = ph4[j];
        float* d = &tile[c * 113 + w4];
        d[0] = v.x; d[1] = v.y; d[2] = v.z; d[3] = v.w;
        v = pw4[j];
        d = &tile[c * 113 + 56 + w4];
        d[0] = v.x; d[1] = v.y; d[2] = v.z; d[3] = v.w;
    }
    __syncthreads();

    int grp = t / 112, l = t - grp * 112;     // grp 0,1 active (4 m each)
    if (grp < 2) {
        int m0 = grp * 4;
        float a0 = 0.f, a1 = 0.f, a2 = 0.f, a3 = 0.f;
        #pragma unroll 8
        for (int c = 0; c < CB; ++c) {
            float v = tile[c * 113 + l];
            a0 += v * lw1[(m0 + 0) * CB + c];
            a1 += v * lw1[(m0 + 1) * CB + c];
            a2 += v * lw1[(m0 + 2) * CB + c];
            a3 += v * lw1[(m0 + 3) * CB + c];
        }
        float acc[4] = {a0, a1, a2, a3};
        #pragma unroll
        for (int k = 0; k < 4; ++k) {
            int m = m0 + k;
            float scale = gamma[m] * rsqrtf(rvar[m] + 1e-5f);
            float val = (acc[k] + b1[m] - rmean[m]) * scale + beta[m];
            yl[m * 112 + l] = fmaxf(val, 0.f);
        }
    }
    if (br == 0 && t >= 128 && t < 192) {     // gate hidden layer (overlaps y)
        int j = t - 128;
        float acc = 0.f;
        for (int c = 0; c < CB; ++c) acc += gap[n * CB + c] * gw1[j * CB + c];
        hid[j] = fmaxf(acc, 0.f);
    }
    __syncthreads();

    if (br == 0 && t == 0) {                  // gate softmax (others do tables)
        float l0 = gb2[0], l1 = gb2[1];
        for (int j = 0; j < 64; ++j) { l0 += hid[j] * gw2[j]; l1 += hid[j] * gw2[64 + j]; }
        float mx = fmaxf(l0, l1);
        float e0 = __expf(l0 - mx), e1 = __expf(l1 - mx);
        float inv = 1.f / (e0 + e1);
        g[n * 2]     = e0 * inv;
        g[n * 2 + 1] = e1 * inv;
    }

    // sigmoid coefficient tables for all 256 channels of this (n,br), unscaled
    for (int idx = t; idx < 14336; idx += 256) {
        int c = idx / 56, l2 = idx - c * 56;
        float hv = bh[c], wvv = bw[c];
        #pragma unroll
        for (int m = 0; m < 8; ++m) {
            hv  += yl[m * 112 + l2]      * wh[c * 8 + m];
            wvv += yl[m * 112 + 56 + l2] * ww[c * 8 + m];
        }
        size_t base = (size_t)(n * 32 + (c >> 3)) * TBLN + (size_t)br * 896 + (c & 7) * 56 + l2;
        tbl[base]       = 1.f / (1.f + __expf(-hv));
        tbl[base + 448] = 1.f / (1.f + __expf(-wvv));
    }
}

// per-element attn dot, tables in LDS
__device__ inline float attn_dot(float4 v, int j,
        const float* h0p, const float* h1p, const float4* a4, const float4* b4) {
    int h = j / 14, wq = j - h * 14;
    float h0 = h0p[h], h1 = h1p[h];
    float4 a = a4[wq], b = b4[wq];
    return v.x * (h0 * a.x + h1 * b.x) + v.y * (h0 * a.y + h1 * b.y)
         + v.z * (h0 * a.z + h1 * b.z) + v.w * (h0 * a.w + h1 * b.w);
}

// ---------------- Kernel 3: tvec = mean(x*attn). 1024 blocks x 8 planes ---------
__global__ __launch_bounds__(256) void k_tsum(const float* __restrict__ x,
        const float* __restrict__ tbl, const float* __restrict__ gbuf,
        float* __restrict__ tvec) {
    __shared__ __align__(16) float tb[1792];  // H0|W0(g0)|H1|W1(g1)
    __shared__ float part[32];
    const int t = threadIdx.x, wv = t >> 6, ln = t & 63;
    const int gq = blockIdx.x;
    const int q0 = gq * 8, qn = q0 >> 8;
    {
        const float g0 = gbuf[qn * 2], g1 = gbuf[qn * 2 + 1];
        const float4* ts = (const float4*)(tbl + (size_t)gq * TBLN);
        float4* td = (float4*)tb;
        for (int i = t; i < 448; i += 256) {
            float4 v = ts[i];
            float s = (i >= 112 && i < 224) ? g0 : ((i >= 336) ? g1 : 1.f);
            v.x *= s; v.y *= s; v.z *= s; v.w *= s;
            td[i] = v;
        }
    }
    __syncthreads();
    const float* cH0 = tb;
    const float* cW0 = tb + 448;
    const float* cH1 = tb + 896;
    const float* cW1 = tb + 1344;

    #pragma unroll 1
    for (int i = 0; i < 8; ++i) {
        const float4* xp4 = (const float4*)(x + (size_t)(q0 + i) * PLANE);
        const float4* a4 = (const float4*)(cW0 + i * 56);
        const float4* b4 = (const float4*)(cW1 + i * 56);
        const float* h0p = cH0 + i * 56;
        const float* h1p = cH1 + i * 56;
        // 3 unconditional + 1 predicated load, all issued before compute
        float4 v0 = xp4[t], v1 = xp4[t + 256], v2 = xp4[t + 512], v3;
        const bool tl = t < 16;
        if (tl) v3 = xp4[t + 768];
        float a0 = attn_dot(v0, t,       h0p, h1p, a4, b4);
        float a1 = attn_dot(v1, t + 256, h0p, h1p, a4, b4);
        float a2 = attn_dot(v2, t + 512, h0p, h1p, a4, b4);
        float a3 = tl ? attn_dot(v3, t + 768, h0p, h1p, a4, b4) : 0.f;
        float s = wave_sum((a0 + a1) + (a2 + a3));
        if (ln == 0) part[i * 4 + wv] = s;    // disjoint slots; synced below
    }
    __syncthreads();
    if (t < 8)
        tvec[q0 + t] = (part[t * 4] + part[t * 4 + 1] + part[t * 4 + 2] + part[t * 4 + 3]) * (1.f / PLANE);
}

// ---------------- Kernel 4: s per block, out = x*(attn*s+1). 1024 blocks --------
__global__ __launch_bounds__(256) void k_final(const float* __restrict__ x,
        const float* __restrict__ tbl, const float* __restrict__ gbuf,
        const float* __restrict__ tvec,
        const float* __restrict__ cw1, const float* __restrict__ cw2,
        const float* __restrict__ cb2, float* __restrict__ out) {
    __shared__ __align__(16) float tb[1792];
    __shared__ __align__(16) float part_h[256];
    __shared__ float hid[64];
    __shared__ float sS[8];
    const int t = threadIdx.x;
    const int gq = blockIdx.x;
    const int q0 = gq * 8, qn = q0 >> 8, qc0 = q0 & 255;
    {
        const float g0 = gbuf[qn * 2], g1 = gbuf[qn * 2 + 1];
        const float4* ts = (const float4*)(tbl + (size_t)gq * TBLN);
        float4* td = (float4*)tb;
        for (int i = t; i < 448; i += 256) {
            float4 v = ts[i];
            float s = (i >= 112 && i < 224) ? g0 : ((i >= 336) ? g1 : 1.f);
            v.x *= s; v.y *= s; v.z *= s; v.w *= s;
            td[i] = v;
        }
    }
    // s-gate hidden layer partials (64 j x 4 c-chunks over all 256 threads)
    {
        int j = t & 63, ch = t >> 6;
        const float* tv = tvec + qn * CB + ch * 64;
        const float* wp = cw1 + (size_t)j * CB + ch * 64;
        float a = 0.f;
        #pragma unroll 8
        for (int c = 0; c < 64; ++c) a += tv[c] * wp[c];
        part_h[j * 4 + ch] = a;
    }
    __syncthreads();
    if (t < 64) {
        float4 p = *(const float4*)(part_h + t * 4);
        hid[t] = fmaxf(p.x + p.y + p.z + p.w, 0.f);
    }
    __syncthreads();
    if (t < 8) {                              // s for this chunk's 8 channels
        int c = qc0 + t;
        float a = cb2[c];
        #pragma unroll 8
        for (int j = 0; j < 64; ++j) a += hid[j] * cw2[c * 64 + j];
        sS[t] = 1.f / (1.f + __expf(-a));
    }
    __syncthreads();

    const float* cH0 = tb;
    const float* cW0 = tb + 448;
    const float* cH1 = tb + 896;
    const float* cW1 = tb + 1344;

    #pragma unroll 1
    for (int i = 0; i < 8; ++i) {
        const float sv = sS[i];
        const float4* xp4 = (const float4*)(x + (size_t)(q0 + i) * PLANE);
        float4* op4 = (float4*)(out + (size_t)(q0 + i) * PLANE);
        const float4* a4 = (const float4*)(cW0 + i * 56);
        const float4* b4 = (const float4*)(cW1 + i * 56);
        const float* h0p = cH0 + i * 56;
        const float* h1p = cH1 + i * 56;
        float4 v0 = xp4[t], v1 = xp4[t + 256], v2 = xp4[t + 512], v3;
        const bool tl = t < 16;
        if (tl) v3 = xp4[t + 768];
        #pragma unroll
        for (int u = 0; u < 4; ++u) {
            if (u == 3 && !tl) break;
            int j = t + u * 256;
            float4 v = (u == 0) ? v0 : (u == 1) ? v1 : (u == 2) ? v2 : v3;
            int h = j / 14, wq = j - h * 14;
            float h0 = h0p[h] * sv, h1 = h1p[h] * sv;
            float4 a = a4[wq], b = b4[wq];
            float4 rr;
            rr.x = v.x * (h0 * a.x + h1 * b.x + 1.f);
            rr.y = v.y * (h0 * a.y + h1 * b.y + 1.f);
            rr.z = v.z * (h0 * a.z + h1 * b.z + 1.f);
            rr.w = v.w * (h0 * a.w + h1 * b.w + 1.f);
            op4[j] = rr;
        }
    }
}

extern "C" void kernel_launch(void* const* d_in, const int* in_sizes, int n_in,
                              void* d_out, int out_size, void* d_ws, size_t ws_size,
                              hipStream_t stream) {
    const float* x     = (const float*)d_in[0];
    const float* w1    = (const float*)d_in[1];
    const float* b1    = (const float*)d_in[2];
    const float* gamma = (const float*)d_in[3];
    const float* beta  = (const float*)d_in[4];
    const float* rmean = (const float*)d_in[5];
    const float* rvar  = (const float*)d_in[6];
    const float* wh    = (const float*)d_in[7];
    const float* bh    = (const float*)d_in[8];
    const float* ww    = (const float*)d_in[9];
    const float* bw    = (const float*)d_in[10];
    const float* gw1   = (const float*)d_in[11];
    const float* gw2   = (const float*)d_in[12];
    const float* gb2   = (const float*)d_in[13];
    const float* cw1   = (const float*)d_in[14];
    const float* cw2   = (const float*)d_in[15];
    const float* cb2   = (const float*)d_in[16];
    float* out = (float*)d_out;

    float* w = (float*)d_ws;
    float* ph   = w;                          // POOLSZ each
    float* pw   = ph + POOLSZ;
    float* mh   = pw + POOLSZ;
    float* mw   = mh + POOLSZ;
    float* gap  = mw + POOLSZ;                // NB*CB
    float* tvec = gap + NB * CB;              // NB*CB
    float* gbuf = tvec + NB * CB;             // 64
    float* tbl  = gbuf + 64;                  // NCHUNK * TBLN

    k_pool<<<4096, 256, 0, stream>>>(x, ph, pw, mh, mw, gap);
    k_branch<<<dim3(NB, 2), 256, 0, stream>>>(ph, pw, mh, mw, gap,
                                              w1, b1, gamma, beta, rmean, rvar,
                                              gw1, gw2, gb2, wh, bh, ww, bw,
                                              tbl, gbuf);
    k_tsum<<<1024, 256, 0, stream>>>(x, tbl, gbuf, tvec);
    k_final<<<1024, 256, 0, stream>>>(x, tbl, gbuf, tvec, cw1, cw2, cb2, out);
}